// Round 9
// baseline (804.425 us; speedup 1.0000x reference)
//
#include <hip/hip_runtime.h>

#define B_ 8
#define S_ 4096
#define IN_ 64
#define HID_ 512
#define NSTEP 12
#define SP_ (S_ + 2)
#define NP_ (B_ * SP_)
#define NTOT (B_ * S_)

typedef unsigned short u16;
typedef __attribute__((ext_vector_type(8))) short bf16x8;
typedef __attribute__((ext_vector_type(4))) float f32x4;
typedef __attribute__((ext_vector_type(16))) float f32x16;

__device__ __forceinline__ u16 f2bf(float f) {
  unsigned u = __float_as_uint(f);
  u += 0x7fffu + ((u >> 16) & 1u);
  return (u16)(u >> 16);
}

__device__ __forceinline__ void gload16(const void* g, void* l) {
  __builtin_amdgcn_global_load_lds((const __attribute__((address_space(1))) void*)g,
                                   (__attribute__((address_space(3))) void*)l, 16, 0, 0);
}

// ---------------- setup: bf16 conversions + weight FRAG layout + pad-row zeroing ----------------
// wfrag: 1536 fragments of 512 u16. frag = ((kk*16 + ig)*16 + ob)*2 + kh holds, at elem
// l*8+j: W_conv[o = ob*32 + (l&31)][i = ig*32 + kh*16 + (l>>5)*8 + j][kk]. Each frag is the
// exact per-lane 16B layout of a 32x32x16 MFMA A-operand -> kernel loads it with one fully
// coalesced global_load_dwordx4 per frag (no LDS round-trip for weights).
__global__ void setup_kernel(const float* __restrict__ x, const float* __restrict__ Wc,
                             const float* __restrict__ Wi, const float* __restrict__ Wo,
                             u16* __restrict__ wfrag, u16* __restrict__ wib,
                             u16* __restrict__ wob, u16* __restrict__ xbf,
                             u16* __restrict__ h0, u16* __restrict__ h1) {
  const int n_wc = 3 * HID_ * HID_;
  const int n_wio = IN_ * HID_;
  const int n_xb = NTOT * IN_;
  const int n_pad = 2 * B_ * 2 * HID_;
  const long total = (long)n_wc + 2 * n_wio + n_xb + n_pad;
  for (long u = (long)blockIdx.x * blockDim.x + threadIdx.x; u < total;
       u += (long)gridDim.x * blockDim.x) {
    long v = u;
    if (v < n_wc) {
      const int frag = (int)(v >> 9), e = (int)(v & 511);
      const int l = e >> 3, j = e & 7;
      const int kh = frag & 1, ob = (frag >> 1) & 15, ig = (frag >> 5) & 15, kk = frag >> 9;
      const int o = ob * 32 + (l & 31);
      const int i = ig * 32 + kh * 16 + (l >> 5) * 8 + j;
      wfrag[v] = f2bf(Wc[((long)o * HID_ + i) * 3 + kk]);
    } else if ((v -= n_wc) < n_wio) {      // wib[i][j] = Wi[j][i]
      int i = (int)(v / IN_), j = (int)(v % IN_);
      wib[v] = f2bf(Wi[j * HID_ + i]);
    } else if ((v -= n_wio) < n_wio) {     // wob[j][i] = Wo[i][j]
      int j = (int)(v / HID_), i = (int)(v % HID_);
      wob[v] = f2bf(Wo[i * IN_ + j]);
    } else if ((v -= n_wio) < n_xb) {
      xbf[v] = f2bf(x[v]);
    } else {
      v -= n_xb;                           // zero pad rows (s=-1 and s=S per batch, both buffers)
      int buf = (int)(v / (B_ * 2 * HID_));
      int r = (int)(v % (B_ * 2 * HID_));
      int b = r / (2 * HID_);
      int q = r % (2 * HID_);
      int side = q / HID_, i = q % HID_;
      long p = (long)b * SP_ + (side ? (S_ + 1) : 0);
      (buf ? h1 : h0)[p * HID_ + i] = 0;
    }
  }
}

// ---------------- proj_in: h0[n][i] = x[n][:] @ W_in[:,i] + b_in  (bf16 MFMA, K=64) ----------------
__global__ __launch_bounds__(256, 2) void proj_in_gemm(const u16* __restrict__ xb,
                                                       const u16* __restrict__ wib,
                                                       const float* __restrict__ bin,
                                                       u16* __restrict__ hout) {
  __shared__ __align__(16) u16 Ab[128 * 64];
  __shared__ __align__(16) u16 Bb[128 * 64];
  const int tid = threadIdx.x, wid = tid >> 6, lane = tid & 63;
  const int nt = blockIdx.x, mt = blockIdx.y;
  const int wr = wid >> 1, wcn = wid & 1, fr = lane & 15, fq = lane >> 4;
#pragma unroll
  for (int c = 0; c < 4; ++c) {
    const int ch = wid * 4 + c;
    const int row = ch * 8 + (lane >> 3), cb = (lane & 7) * 8;
    gload16(wib + (mt * 128 + row) * 64 + cb, &Ab[ch * 512]);
    gload16(xb + ((long)nt * 128 + row) * 64 + cb, &Bb[ch * 512]);
  }
  f32x4 acc[4][4];
#pragma unroll
  for (int m = 0; m < 4; ++m)
#pragma unroll
    for (int n = 0; n < 4; ++n) acc[m][n] = {0.f, 0.f, 0.f, 0.f};
  __syncthreads();
#pragma unroll
  for (int t = 0; t < 2; ++t) {
    const int j0 = t * 32;
    bf16x8 af[4], bfv[4];
#pragma unroll
    for (int m = 0; m < 4; ++m)
      af[m] = *(const bf16x8*)&Ab[(wr * 64 + m * 16 + fr) * 64 + j0 + fq * 8];
#pragma unroll
    for (int n = 0; n < 4; ++n)
      bfv[n] = *(const bf16x8*)&Bb[(wcn * 64 + n * 16 + fr) * 64 + j0 + fq * 8];
#pragma unroll
    for (int m = 0; m < 4; ++m)
#pragma unroll
      for (int n = 0; n < 4; ++n)
        acc[m][n] = __builtin_amdgcn_mfma_f32_16x16x32_bf16(af[m], bfv[n], acc[m][n], 0, 0, 0);
  }
  const int n0 = nt * 128;
  const int bb = n0 / S_, s0v = n0 % S_;
  const int prow = bb * SP_ + s0v + 1;
#pragma unroll
  for (int m = 0; m < 4; ++m) {
    const int i = mt * 128 + wr * 64 + m * 16 + fq * 4;
    const float4 bias = *(const float4*)&bin[i];
#pragma unroll
    for (int n = 0; n < 4; ++n) {
      const int nl = wcn * 64 + n * 16 + fr;
      const long p = prow + nl;
      union { u16 q[4]; uint2 v; } u;
      u.q[0] = f2bf(acc[m][n][0] + bias.x);
      u.q[1] = f2bf(acc[m][n][1] + bias.y);
      u.q[2] = f2bf(acc[m][n][2] + bias.z);
      u.q[3] = f2bf(acc[m][n][3] + bias.w);
      *(uint2*)&hout[p * HID_ + i] = u.v;
    }
  }
}

// ---------------- conv step: 256o x 128n tile, 4 waves, A-in-reg, B-in-LDS ----------------
// C[o,n] = relu(sum_{k,i} W[o,i,k] h[i,n+k-1] + b). 32x32x16 MFMA (R5/R6-verified maps).
// Per wave: C = 128x64 (mf 4 x nf 2), acc[4][2] f32x16 = 128 VGPR.
// A: global->reg direct from wfrag (coalesced dwordx4, L1/L2-hot), dbuf'd across tiles.
// B: LDS 4 bufs x 8KB ([128 n][32 i] row-major, col-XOR ((row>>1)&3)<<4, 4-way conflict),
//    R3-style coalesced staging with inverse-swizzled source, depth-3 prefetch.
// 32 KB LDS + 256 thr -> 2 blocks/CU; each SIMD hosts waves of BOTH blocks ->
// independent barrier domains dephase -> LDS/MFMA cross-block overlap (m114).
// vmcnt FIFO/body (a=8 loads, Bst=2): entry [Bst(t+1)2, a(t)8, Bst(t+2)2]=12;
// vmcnt(10) retires Bst(t+1) -> barrier -> b-reads(t) -> a(t+1) -> Bst(t+3) ->
// vmcnt(12) retires a(t) -> MFMA. Prologue a(0),Bst(0,1,2): vmcnt(4). Never vmcnt(0).
#define SB __builtin_amdgcn_sched_barrier(0)

#define BODY9(T, AC, AN) do {                                                   \
    asm volatile("s_waitcnt vmcnt(10)" ::: "memory"); SB;                       \
    __builtin_amdgcn_s_barrier(); SB;                                           \
    { const char* _bp = (const char*)smem + ((T) & 3) * 8192;                   \
      bf[0][0] = *(const bf16x8*)(_bp + bbase + c0);                            \
      bf[0][1] = *(const bf16x8*)(_bp + bbase + c1);                            \
      bf[1][0] = *(const bf16x8*)(_bp + bbase + 2048 + c0);                     \
      bf[1][1] = *(const bf16x8*)(_bp + bbase + 2048 + c1); } SB;               \
    aload((T) + 1, AN); SB;                                                     \
    stage((T) + 3); SB;                                                         \
    asm volatile("s_waitcnt vmcnt(12)" ::: "memory"); SB;                       \
    __builtin_amdgcn_s_setprio(1);                                              \
    _Pragma("unroll")                                                           \
    for (int _kh = 0; _kh < 2; ++_kh)                                           \
      _Pragma("unroll")                                                         \
      for (int _mf = 0; _mf < 4; ++_mf)                                         \
        _Pragma("unroll")                                                       \
        for (int _nf = 0; _nf < 2; ++_nf)                                       \
          acc[_mf][_nf] = __builtin_amdgcn_mfma_f32_32x32x16_bf16(              \
              AC[_kh][_mf], bf[_nf][_kh], acc[_mf][_nf], 0, 0, 0);              \
    __builtin_amdgcn_s_setprio(0); SB;                                          \
  } while (0)

__global__ __launch_bounds__(256, 2) void conv_gemm9(const u16* __restrict__ hin,
                                                     u16* __restrict__ hout,
                                                     const u16* __restrict__ wfrag,
                                                     const float* __restrict__ bconv) {
  extern __shared__ __align__(16) u16 smem[];
  const int tid = threadIdx.x;
  const int w = tid >> 6, lane = tid & 63;
  const int wm = w >> 1, wn = w & 1;          // 2 x 2 wave grid; per-wave C = 128 x 64
  const int r32 = lane & 31, khi = lane >> 5;
  const int mbase = blockIdx.y * 256;
  const int obase = blockIdx.y * 8 + wm * 4;  // o-block (32-row units) for this wave
  const int n0 = blockIdx.x * 128;
  const int bb = n0 / S_, s0 = n0 % S_;
  const int prow0 = bb * SP_ + s0;            // tap-k B rows start at prow0+k

  // B staging per-lane coords: chunk c dest byte = c*4096 + w*1024 + lane*16;
  // row = dest>>6; source col = ((lane&3)*16 ^ ((row>>1)&3)<<4)>>1 (inverse swizzle).
  int srow[2], scole[2];
#pragma unroll
  for (int c = 0; c < 2; ++c) {
    srow[c] = c * 64 + w * 16 + (lane >> 2);
    scole[c] = ((((lane & 3) * 16) ^ (((srow[c] >> 1) & 3) << 4)) >> 1);
  }

  auto stage = [&](int t) {                   // stage B K-tile t into buf t&3
    int u = t > 47 ? 47 : t;                  // clamp source only (dummy tail stages)
    const int kk = u % 3;                     // tap-inner: B re-reads L2-hot
    const int i0 = (u / 3) * 32;
    char* base = (char*)smem + (t & 3) * 8192;
    gload16(hin + (size_t)(prow0 + kk + srow[0]) * HID_ + i0 + scole[0], base + w * 1024);
    gload16(hin + (size_t)(prow0 + kk + srow[1]) * HID_ + i0 + scole[1], base + 4096 + w * 1024);
  };

  bf16x8 aA[2][4], aB[2][4], bf[2][2];

  auto aload = [&](int t, bf16x8 A[2][4]) {   // A frags of K-tile t -> regs (coalesced)
    int u = t > 47 ? 47 : t;
    const int kk = u % 3, ig = u / 3;
    const u16* fb = wfrag + ((size_t)(((kk * 16 + ig) * 16 + obase) * 2) << 9) + (lane << 3);
#pragma unroll
    for (int mf = 0; mf < 4; ++mf)
#pragma unroll
      for (int kh = 0; kh < 2; ++kh)
        A[kh][mf] = *(const bf16x8*)(fb + ((mf * 2 + kh) << 9));
  };

  f32x16 acc[4][2];
#pragma unroll
  for (int mf = 0; mf < 4; ++mf)
#pragma unroll
    for (int nf = 0; nf < 2; ++nf)
#pragma unroll
      for (int e = 0; e < 16; ++e) acc[mf][nf][e] = 0.f;

  // b-read constants: row = wn*64 + nf*32 + r32 (byte row*64); col slot = kh*2+khi,
  // XOR'd by g = ((r32>>1)&3)<<4 (row>>1 mod 4 invariant to wn*64/nf*32 offsets).
  const int g = ((r32 >> 1) & 3) << 4;
  const int c0 = ((khi * 16) ^ (g & 16)) + (g & 32);
  const int c1 = ((khi * 16) ^ (g & 16)) + (32 ^ (g & 32));
  const int bbase = (wn * 64 + r32) * 64;

  // prologue: a(0) -> set A; stage B tiles 0,1,2; prove a0+Bst0; barrier.
  aload(0, aA); SB;
  stage(0); stage(1); stage(2); SB;
  asm volatile("s_waitcnt vmcnt(4)" ::: "memory"); SB;
  __builtin_amdgcn_s_barrier(); SB;

#pragma unroll 1
  for (int j = 0; j < 24; ++j) {
    BODY9(2 * j,     aA, aB);
    BODY9(2 * j + 1, aB, aA);
  }

  // epilogue: bias + relu + bf16 store. C/D 32x32 map (R5/R6-verified): col=lane&31,
  // row=(reg&3)+8*(reg>>2)+4*(lane>>5).
#pragma unroll
  for (int mf = 0; mf < 4; ++mf)
#pragma unroll
    for (int gq = 0; gq < 4; ++gq) {
      const int o = mbase + wm * 128 + mf * 32 + gq * 8 + khi * 4;
      const float4 bias = *(const float4*)&bconv[o];
#pragma unroll
      for (int nf = 0; nf < 2; ++nf) {
        const int n = wn * 64 + nf * 32 + r32;
        const long p = (long)prow0 + 1 + n;
        union { u16 q[4]; uint2 v; } uo;
        uo.q[0] = f2bf(fmaxf(acc[mf][nf][gq * 4 + 0] + bias.x, 0.f));
        uo.q[1] = f2bf(fmaxf(acc[mf][nf][gq * 4 + 1] + bias.y, 0.f));
        uo.q[2] = f2bf(fmaxf(acc[mf][nf][gq * 4 + 2] + bias.z, 0.f));
        uo.q[3] = f2bf(fmaxf(acc[mf][nf][gq * 4 + 3] + bias.w, 0.f));
        *(uint2*)&hout[p * HID_ + o] = uo.v;
      }
    }
}

// ---------------- proj_out: out[n][j] = h[n][:] @ W_out[:,j] + b_out (fp32 out) ----------------
__global__ __launch_bounds__(256, 2) void proj_out_gemm(const u16* __restrict__ hin,
                                                        const u16* __restrict__ wob,
                                                        const float* __restrict__ bout,
                                                        float* __restrict__ out) {
  __shared__ __align__(16) u16 Ab[2][128 * 32];   // [n][i]
  __shared__ __align__(16) u16 Bb[2][64 * 32];    // [j][i]
  const int tid = threadIdx.x, wid = tid >> 6, lane = tid & 63;
  const int nt = blockIdx.x;
  const int bb = (nt * 128) / S_, s0v = (nt * 128) % S_;
  const int prow0 = bb * SP_ + s0v + 1;
  const int l4 = lane >> 2, lb = (lane & 3) * 8;
  const int fr = lane & 15, fq = lane >> 4;

  f32x4 acc[2][4];
#pragma unroll
  for (int m = 0; m < 2; ++m)
#pragma unroll
    for (int n = 0; n < 4; ++n) acc[m][n] = {0.f, 0.f, 0.f, 0.f};

  auto stage = [&](int buf, int t) {
    const int i0 = t * 32;
#pragma unroll
    for (int c = 0; c < 2; ++c) {
      const int ch = wid * 2 + c;
      gload16(hin + (long)(prow0 + ch * 16 + l4) * HID_ + i0 + lb, &Ab[buf][ch * 512]);
    }
    gload16(wob + (wid * 16 + l4) * HID_ + i0 + lb, &Bb[buf][wid * 512]);
  };

  stage(0, 0);
  __syncthreads();
  for (int t = 0; t < 16; ++t) {
    const int cur = t & 1;
    if (t < 15) stage(cur ^ 1, t + 1);
    bf16x8 af[2], bfv[4];
#pragma unroll
    for (int m = 0; m < 2; ++m)
      af[m] = *(const bf16x8*)&Ab[cur][(wid * 32 + m * 16 + fr) * 32 + fq * 8];
#pragma unroll
    for (int j = 0; j < 4; ++j)
      bfv[j] = *(const bf16x8*)&Bb[cur][(j * 16 + fr) * 32 + fq * 8];
#pragma unroll
    for (int m = 0; m < 2; ++m)
#pragma unroll
      for (int j = 0; j < 4; ++j)
        acc[m][j] = __builtin_amdgcn_mfma_f32_16x16x32_bf16(af[m], bfv[j], acc[m][j], 0, 0, 0);
    __syncthreads();
  }
  const int n0 = nt * 128;
#pragma unroll
  for (int m = 0; m < 2; ++m) {
    const int nbase = n0 + wid * 32 + m * 16 + fq * 4;
#pragma unroll
    for (int jf = 0; jf < 4; ++jf) {
      const int j = jf * 16 + fr;
      const float bj = bout[j];
#pragma unroll
      for (int r = 0; r < 4; ++r)
        out[(long)(nbase + r) * IN_ + j] = acc[m][jf][r] + bj;
    }
  }
}

extern "C" void kernel_launch(void* const* d_in, const int* in_sizes, int n_in,
                              void* d_out, int out_size, void* d_ws, size_t ws_size,
                              hipStream_t stream) {
  (void)in_sizes; (void)n_in; (void)out_size; (void)ws_size;
  const float* x = (const float*)d_in[0];
  const float* W_in = (const float*)d_in[1];
  const float* b_in = (const float*)d_in[2];
  const float* W_conv = (const float*)d_in[3];
  const float* b_conv = (const float*)d_in[4];
  const float* W_out = (const float*)d_in[5];
  const float* b_out = (const float*)d_in[6];
  float* out = (float*)d_out;
  char* ws = (char*)d_ws;

  const size_t hbytes = (size_t)NP_ * HID_ * sizeof(u16);        // 33,570,816 B
  u16* h0 = (u16*)ws;
  u16* h1 = (u16*)(ws + hbytes);
  u16* wfrag = (u16*)(ws + 2 * hbytes);
  u16* wib = (u16*)(ws + 2 * hbytes + (size_t)3 * HID_ * HID_ * 2);
  u16* wob = (u16*)(ws + 2 * hbytes + ((size_t)3 * HID_ * HID_ + IN_ * HID_) * 2);
  u16* xbf = (u16*)(ws + 2 * hbytes + ((size_t)3 * HID_ * HID_ + 2 * IN_ * HID_) * 2);

  setup_kernel<<<2048, 256, 0, stream>>>(x, W_conv, W_in, W_out, wfrag, wib, wob, xbf, h0, h1);
  proj_in_gemm<<<dim3(NTOT / 128, HID_ / 128), 256, 0, stream>>>(xbf, wib, b_in, h0);
  const u16* cin = h0;
  u16* cout = h1;
  for (int s = 0; s < NSTEP; ++s) {
    conv_gemm9<<<dim3(NTOT / 128, HID_ / 256), 256, 32768, stream>>>(cin, cout, wfrag, b_conv);
    u16* t = (u16*)cin; cin = cout; cout = t;
  }
  proj_out_gemm<<<NTOT / 128, 256, 0, stream>>>(cin, wob, b_out, out);
}

// Round 10
// 663.491 us; speedup vs baseline: 1.2124x; 1.2124x over previous
//
#include <hip/hip_runtime.h>

#define B_ 8
#define S_ 4096
#define IN_ 64
#define HID_ 512
#define NSTEP 12
#define SP_ (S_ + 2)
#define NP_ (B_ * SP_)
#define NTOT (B_ * S_)

typedef unsigned short u16;
typedef __attribute__((ext_vector_type(8))) short bf16x8;
typedef __attribute__((ext_vector_type(4))) float f32x4;

__device__ __forceinline__ u16 f2bf(float f) {
  unsigned u = __float_as_uint(f);
  u += 0x7fffu + ((u >> 16) & 1u);
  return (u16)(u >> 16);
}

__device__ __forceinline__ void gload16(const void* g, void* l) {
  __builtin_amdgcn_global_load_lds((const __attribute__((address_space(1))) void*)g,
                                   (__attribute__((address_space(3))) void*)l, 16, 0, 0);
}

// ---------------- setup: bf16 conversions + weight transposes + pad-row zeroing ----------------
__global__ void setup_kernel(const float* __restrict__ x, const float* __restrict__ Wc,
                             const float* __restrict__ Wi, const float* __restrict__ Wo,
                             u16* __restrict__ wcb, u16* __restrict__ wib,
                             u16* __restrict__ wob, u16* __restrict__ xbf,
                             u16* __restrict__ h0, u16* __restrict__ h1) {
  const int n_wc = 3 * HID_ * HID_;       // wcb[k][o][i] = Wc[o][i][k]
  const int n_wio = IN_ * HID_;
  const int n_xb = NTOT * IN_;
  const int n_pad = 2 * B_ * 2 * HID_;
  const long total = (long)n_wc + 2 * n_wio + n_xb + n_pad;
  for (long u = (long)blockIdx.x * blockDim.x + threadIdx.x; u < total;
       u += (long)gridDim.x * blockDim.x) {
    long v = u;
    if (v < n_wc) {
      int k = (int)(v / (HID_ * HID_));
      int rem = (int)(v % (HID_ * HID_));
      int o = rem / HID_, i = rem % HID_;
      wcb[v] = f2bf(Wc[((long)o * HID_ + i) * 3 + k]);
    } else if ((v -= n_wc) < n_wio) {      // wib[i][j] = Wi[j][i]
      int i = (int)(v / IN_), j = (int)(v % IN_);
      wib[v] = f2bf(Wi[j * HID_ + i]);
    } else if ((v -= n_wio) < n_wio) {     // wob[j][i] = Wo[i][j]
      int j = (int)(v / HID_), i = (int)(v % HID_);
      wob[v] = f2bf(Wo[i * IN_ + j]);
    } else if ((v -= n_wio) < n_xb) {
      xbf[v] = f2bf(x[v]);
    } else {
      v -= n_xb;                           // zero pad rows (s=-1 and s=S per batch, both buffers)
      int buf = (int)(v / (B_ * 2 * HID_));
      int r = (int)(v % (B_ * 2 * HID_));
      int b = r / (2 * HID_);
      int q = r % (2 * HID_);
      int side = q / HID_, i = q % HID_;
      long p = (long)b * SP_ + (side ? (S_ + 1) : 0);
      (buf ? h1 : h0)[p * HID_ + i] = 0;
    }
  }
}

// ---------------- proj_in: h0[n][i] = x[n][:] @ W_in[:,i] + b_in  (bf16 MFMA, K=64) ----------------
__global__ __launch_bounds__(256, 2) void proj_in_gemm(const u16* __restrict__ xb,
                                                       const u16* __restrict__ wib,
                                                       const float* __restrict__ bin,
                                                       u16* __restrict__ hout) {
  __shared__ __align__(16) u16 Ab[128 * 64];
  __shared__ __align__(16) u16 Bb[128 * 64];
  const int tid = threadIdx.x, wid = tid >> 6, lane = tid & 63;
  const int nt = blockIdx.x, mt = blockIdx.y;
  const int wr = wid >> 1, wcn = wid & 1, fr = lane & 15, fq = lane >> 4;
#pragma unroll
  for (int c = 0; c < 4; ++c) {
    const int ch = wid * 4 + c;
    const int row = ch * 8 + (lane >> 3), cb = (lane & 7) * 8;
    gload16(wib + (mt * 128 + row) * 64 + cb, &Ab[ch * 512]);
    gload16(xb + ((long)nt * 128 + row) * 64 + cb, &Bb[ch * 512]);
  }
  f32x4 acc[4][4];
#pragma unroll
  for (int m = 0; m < 4; ++m)
#pragma unroll
    for (int n = 0; n < 4; ++n) acc[m][n] = {0.f, 0.f, 0.f, 0.f};
  __syncthreads();
#pragma unroll
  for (int t = 0; t < 2; ++t) {
    const int j0 = t * 32;
    bf16x8 af[4], bfv[4];
#pragma unroll
    for (int m = 0; m < 4; ++m)
      af[m] = *(const bf16x8*)&Ab[(wr * 64 + m * 16 + fr) * 64 + j0 + fq * 8];
#pragma unroll
    for (int n = 0; n < 4; ++n)
      bfv[n] = *(const bf16x8*)&Bb[(wcn * 64 + n * 16 + fr) * 64 + j0 + fq * 8];
#pragma unroll
    for (int m = 0; m < 4; ++m)
#pragma unroll
      for (int n = 0; n < 4; ++n)
        acc[m][n] = __builtin_amdgcn_mfma_f32_16x16x32_bf16(af[m], bfv[n], acc[m][n], 0, 0, 0);
  }
  const int n0 = nt * 128;
  const int bb = n0 / S_, s0v = n0 % S_;
  const int prow = bb * SP_ + s0v + 1;
#pragma unroll
  for (int m = 0; m < 4; ++m) {
    const int i = mt * 128 + wr * 64 + m * 16 + fq * 4;
    const float4 bias = *(const float4*)&bin[i];
#pragma unroll
    for (int n = 0; n < 4; ++n) {
      const int nl = wcn * 64 + n * 16 + fr;
      const long p = prow + nl;
      union { u16 q[4]; uint2 v; } u;
      u.q[0] = f2bf(acc[m][n][0] + bias.x);
      u.q[1] = f2bf(acc[m][n][1] + bias.y);
      u.q[2] = f2bf(acc[m][n][2] + bias.z);
      u.q[3] = f2bf(acc[m][n][3] + bias.w);
      *(uint2*)&hout[p * HID_ + i] = u.v;
    }
  }
}

// ---------------- conv step: 256o x 128n tile, 4 waves, 2 blocks/CU for TLP overlap ----------
// C[o,n] = relu(sum_{k,i} W[o,i,k] h[i,n+k-1] + b), bf16 in/out. 16x16x32 MFMA.
// K-units u = 0..47: tap kk=u%3, i-slice i0=(u/3)*32 (tap-inner: B re-reads L2-hot).
// Per wave (2x2 grid): C = 128x64, acc[8][4] f32x4 = 128 AGPR; ~110 VGPR -> 2 waves/SIMD.
// LDS: 2 bufs x 24KB (A 256x32 16KB + B 128x32 8KB), 64-B rows, R3-verified swizzle
// byte ^= ((row>>1)&3)<<4 on source + read sides -> 0 bank conflicts.
// 48KB LDS + 240 regs -> TWO independent 4-wave blocks per CU: each SIMD hosts one
// wave of each block in separate barrier domains -> block A's ds_read service
// overlaps block B's MFMA burst (m114 mechanism) without any intra-block heroics.
// Body(T): barrier (all waves done reading buf(T-1)) -> stage(T+1) (6 gload16) ->
// vmcnt(6) (retires stage(T), never 0) -> barrier (tile T staged) -> 12 ds_reads ->
// MFMA (compiler auto-lgkm). Tail stage clamps source u (dummy re-stage).
#define SB __builtin_amdgcn_sched_barrier(0)

__global__ __launch_bounds__(256, 2) void conv_gemm10(const u16* __restrict__ hin,
                                                      u16* __restrict__ hout,
                                                      const u16* __restrict__ wcb,
                                                      const float* __restrict__ bconv) {
  extern __shared__ __align__(16) u16 smem[];   // 49152 B
  const int tid = threadIdx.x;
  const int w = tid >> 6, lane = tid & 63;
  const int wm = w >> 1, wn = w & 1;            // 2 x 2 wave grid; per-wave C = 128 x 64
  const int fr = lane & 15, fq = lane >> 4;
  const int mbase = blockIdx.y * 256;
  const int n0 = blockIdx.x * 128;
  const int bb = n0 / S_, s0 = n0 % S_;
  const int prow0 = bb * SP_ + s0;              // tap-k B rows start at prow0+k

  // staging coords: chunk dest byte = c*4096 + tid*16 -> row = c*64 + (tid>>2),
  // col byte = (tid&3)*16 ^ ((row>>1)&3)<<4 (inverse swizzle; (row>>1)&3 == (trow>>1)&3).
  const int trow = tid >> 2;                    // 0..63
  const int cole = (((tid & 3) * 16) ^ (((trow >> 1) & 3) << 4)) >> 1;

  auto stage = [&](int t) {
    int u = t > 47 ? 47 : t;                    // tail clamp keeps vmcnt uniform
    const int kk = u % 3;
    const int i0 = (u / 3) * 32;
    char* base = (char*)smem + (t & 1) * 24576;
    const u16* ga = wcb + (size_t)kk * (HID_ * HID_) + (size_t)(mbase + trow) * HID_ + i0 + cole;
    const u16* gb = hin + (size_t)(prow0 + kk + trow) * HID_ + i0 + cole;
    const int wd = w * 1024;
    gload16(ga,                 base + wd);            // A rows   0- 63
    gload16(ga +  64 * HID_,    base + 4096 + wd);     // A rows  64-127
    gload16(ga + 128 * HID_,    base + 8192 + wd);     // A rows 128-191
    gload16(ga + 192 * HID_,    base + 12288 + wd);    // A rows 192-255
    gload16(gb,                 base + 16384 + wd);    // B rows   0- 63
    gload16(gb +  64 * HID_,    base + 20480 + wd);    // B rows  64-127
  };

  f32x4 acc[8][4];
#pragma unroll
  for (int m = 0; m < 8; ++m)
#pragma unroll
    for (int n = 0; n < 4; ++n) acc[m][n] = {0.f, 0.f, 0.f, 0.f};

  // ds_read constants (R3-verified, 0 conflicts): byte = row*64 + fq*16,
  // XOR = ((fr>>1)&3)<<4 (row>>1 mod 4 depends only on fr).
  const int swzb = ((fr >> 1) & 3) << 4;
  const int aoffs = (((wm * 128 + fr) * 64 + fq * 16)) ^ swzb;
  const int boffs = (((wn * 64 + fr) * 64 + fq * 16)) ^ swzb;

  stage(0);                                     // prologue: 6 loads outstanding

#pragma unroll 6
  for (int t = 0; t < 48; ++t) {
    SB;
    __builtin_amdgcn_s_barrier();               // all waves done reading buf (t-1)&1
    SB;
    stage(t + 1);                               // refill the freed buffer
    SB;
    asm volatile("s_waitcnt vmcnt(6)" ::: "memory");  // tile t staged (t+1 flies)
    SB;
    __builtin_amdgcn_s_barrier();               // tile t visible to all waves
    SB;

    const char* A = (const char*)smem + (t & 1) * 24576;
    bf16x8 af[8], bf[4];
#pragma unroll
    for (int m = 0; m < 8; ++m)
      af[m] = *(const bf16x8*)(A + aoffs + m * 1024);
#pragma unroll
    for (int n = 0; n < 4; ++n)
      bf[n] = *(const bf16x8*)(A + 16384 + boffs + n * 1024);
    SB;
    __builtin_amdgcn_s_setprio(1);
#pragma unroll
    for (int m = 0; m < 8; ++m)
#pragma unroll
      for (int n = 0; n < 4; ++n)
        acc[m][n] = __builtin_amdgcn_mfma_f32_16x16x32_bf16(af[m], bf[n], acc[m][n], 0, 0, 0);
    __builtin_amdgcn_s_setprio(0);
    SB;
  }

  // epilogue: bias + relu + bf16 store (4 consecutive channels per 8B store)
#pragma unroll
  for (int m = 0; m < 8; ++m) {
    const int o = mbase + wm * 128 + m * 16 + fq * 4;
    const float4 bias = *(const float4*)&bconv[o];
#pragma unroll
    for (int n = 0; n < 4; ++n) {
      const int nl = wn * 64 + n * 16 + fr;
      const long p = (long)prow0 + 1 + nl;
      union { u16 q[4]; uint2 v; } u;
      u.q[0] = f2bf(fmaxf(acc[m][n][0] + bias.x, 0.f));
      u.q[1] = f2bf(fmaxf(acc[m][n][1] + bias.y, 0.f));
      u.q[2] = f2bf(fmaxf(acc[m][n][2] + bias.z, 0.f));
      u.q[3] = f2bf(fmaxf(acc[m][n][3] + bias.w, 0.f));
      *(uint2*)&hout[p * HID_ + o] = u.v;
    }
  }
}

// ---------------- proj_out: out[n][j] = h[n][:] @ W_out[:,j] + b_out (fp32 out) ----------------
__global__ __launch_bounds__(256, 2) void proj_out_gemm(const u16* __restrict__ hin,
                                                        const u16* __restrict__ wob,
                                                        const float* __restrict__ bout,
                                                        float* __restrict__ out) {
  __shared__ __align__(16) u16 Ab[2][128 * 32];   // [n][i]
  __shared__ __align__(16) u16 Bb[2][64 * 32];    // [j][i]
  const int tid = threadIdx.x, wid = tid >> 6, lane = tid & 63;
  const int nt = blockIdx.x;
  const int bb = (nt * 128) / S_, s0v = (nt * 128) % S_;
  const int prow0 = bb * SP_ + s0v + 1;
  const int l4 = lane >> 2, lb = (lane & 3) * 8;
  const int fr = lane & 15, fq = lane >> 4;

  f32x4 acc[2][4];
#pragma unroll
  for (int m = 0; m < 2; ++m)
#pragma unroll
    for (int n = 0; n < 4; ++n) acc[m][n] = {0.f, 0.f, 0.f, 0.f};

  auto stage = [&](int buf, int t) {
    const int i0 = t * 32;
#pragma unroll
    for (int c = 0; c < 2; ++c) {
      const int ch = wid * 2 + c;
      gload16(hin + (long)(prow0 + ch * 16 + l4) * HID_ + i0 + lb, &Ab[buf][ch * 512]);
    }
    gload16(wob + (wid * 16 + l4) * HID_ + i0 + lb, &Bb[buf][wid * 512]);
  };

  stage(0, 0);
  __syncthreads();
  for (int t = 0; t < 16; ++t) {
    const int cur = t & 1;
    if (t < 15) stage(cur ^ 1, t + 1);
    bf16x8 af[2], bfv[4];
#pragma unroll
    for (int m = 0; m < 2; ++m)
      af[m] = *(const bf16x8*)&Ab[cur][(wid * 32 + m * 16 + fr) * 32 + fq * 8];
#pragma unroll
    for (int j = 0; j < 4; ++j)
      bfv[j] = *(const bf16x8*)&Bb[cur][(j * 16 + fr) * 32 + fq * 8];
#pragma unroll
    for (int m = 0; m < 2; ++m)
#pragma unroll
      for (int j = 0; j < 4; ++j)
        acc[m][j] = __builtin_amdgcn_mfma_f32_16x16x32_bf16(af[m], bfv[j], acc[m][j], 0, 0, 0);
    __syncthreads();
  }
  const int n0 = nt * 128;
#pragma unroll
  for (int m = 0; m < 2; ++m) {
    const int nbase = n0 + wid * 32 + m * 16 + fq * 4;
#pragma unroll
    for (int jf = 0; jf < 4; ++jf) {
      const int j = jf * 16 + fr;
      const float bj = bout[j];
#pragma unroll
      for (int r = 0; r < 4; ++r)
        out[(long)(nbase + r) * IN_ + j] = acc[m][jf][r] + bj;
    }
  }
}

extern "C" void kernel_launch(void* const* d_in, const int* in_sizes, int n_in,
                              void* d_out, int out_size, void* d_ws, size_t ws_size,
                              hipStream_t stream) {
  (void)in_sizes; (void)n_in; (void)out_size; (void)ws_size;
  const float* x = (const float*)d_in[0];
  const float* W_in = (const float*)d_in[1];
  const float* b_in = (const float*)d_in[2];
  const float* W_conv = (const float*)d_in[3];
  const float* b_conv = (const float*)d_in[4];
  const float* W_out = (const float*)d_in[5];
  const float* b_out = (const float*)d_in[6];
  float* out = (float*)d_out;
  char* ws = (char*)d_ws;

  const size_t hbytes = (size_t)NP_ * HID_ * sizeof(u16);        // 33,570,816 B
  u16* h0 = (u16*)ws;
  u16* h1 = (u16*)(ws + hbytes);
  u16* wcb = (u16*)(ws + 2 * hbytes);
  u16* wib = (u16*)(ws + 2 * hbytes + (size_t)3 * HID_ * HID_ * 2);
  u16* wob = (u16*)(ws + 2 * hbytes + ((size_t)3 * HID_ * HID_ + IN_ * HID_) * 2);
  u16* xbf = (u16*)(ws + 2 * hbytes + ((size_t)3 * HID_ * HID_ + 2 * IN_ * HID_) * 2);

  setup_kernel<<<2048, 256, 0, stream>>>(x, W_conv, W_in, W_out, wcb, wib, wob, xbf, h0, h1);
  proj_in_gemm<<<dim3(NTOT / 128, HID_ / 128), 256, 0, stream>>>(xbf, wib, b_in, h0);
  const u16* cin = h0;
  u16* cout = h1;
  for (int s = 0; s < NSTEP; ++s) {
    conv_gemm10<<<dim3(NTOT / 128, HID_ / 256), 256, 49152, stream>>>(cin, cout, wcb, b_conv);
    u16* t = (u16*)cin; cin = cout; cout = t;
  }
  proj_out_gemm<<<NTOT / 128, 256, 0, stream>>>(cin, wob, b_out, out);
}